// Round 8
// baseline (560.078 us; speedup 1.0000x reference)
//
#include <hip/hip_runtime.h>
#include <cstdint>

#define NN 100000
#define NE 1600000
#define INDIM 165
#define HID 64

// dst-bucket partition: bucket = dst >> BSH, BNODES nodes per bucket
constexpr int BSH = 7;
constexpr int BNODES = 128;               // 1 << BSH
constexpr int NBUK = (NN + BNODES - 1) / BNODES; // 782
constexpr int SC_CHUNK = 8192;            // edges per scatter block

// ---------------- bucket histogram ----------------

__global__ __launch_bounds__(256) void k_bhist(const int* __restrict__ dst,
                                               int* __restrict__ bhist, int ne) {
    __shared__ int h[NBUK];
    for (int b = threadIdx.x; b < NBUK; b += 256) h[b] = 0;
    __syncthreads();
    for (int e = blockIdx.x * blockDim.x + threadIdx.x; e < ne;
         e += gridDim.x * blockDim.x)
        atomicAdd(&h[dst[e] >> BSH], 1);
    __syncthreads();
    for (int b = threadIdx.x; b < NBUK; b += 256)
        if (h[b]) atomicAdd(&bhist[b], h[b]);
}

// ---------------- scan of 782 bucket counts (single block) ----------------

__global__ __launch_bounds__(256) void k_bscan(const int* __restrict__ bhist,
                                               int* __restrict__ bbase,
                                               int* __restrict__ bcursor) {
    __shared__ int wsum[4];
    const int tid = threadIdx.x, lane = tid & 63, wid = tid >> 6;
    int v[4];
    int tsum = 0;
#pragma unroll
    for (int i = 0; i < 4; ++i) {
        int idx = tid * 4 + i;
        v[i] = (idx < NBUK) ? bhist[idx] : 0;
        tsum += v[i];
    }
    int x = tsum;
#pragma unroll
    for (int off = 1; off < 64; off <<= 1) {
        int y = __shfl_up(x, off, 64);
        if (lane >= off) x += y;
    }
    if (lane == 63) wsum[wid] = x;
    __syncthreads();
    int woff = 0;
#pragma unroll
    for (int w = 0; w < 4; ++w)
        if (w < wid) woff += wsum[w];
    int run = woff + x - tsum;
#pragma unroll
    for (int i = 0; i < 4; ++i) {
        int idx = tid * 4 + i;
        if (idx < NBUK) { bbase[idx] = run; bcursor[idx] = run; }
        run += v[i];
    }
    if (tid == 255) bbase[NBUK] = woff + x; // grand total (= ne)
}

// ---------------- partition edges into bucket-major (src,dst) pairs --------

__global__ __launch_bounds__(256) void k_scatter(const int* __restrict__ src,
                                                 const int* __restrict__ dst,
                                                 int* __restrict__ bcursor,
                                                 int2* __restrict__ E2, int ne) {
    __shared__ int hist[NBUK];
    __shared__ int base[NBUK];
    const int tid = threadIdx.x;
    const int cs = blockIdx.x * SC_CHUNK;
    for (int b = tid; b < NBUK; b += 256) hist[b] = 0;
    __syncthreads();
    unsigned pack[SC_CHUNK / 256];
#pragma unroll 8
    for (int i = 0; i < SC_CHUNK / 256; ++i) {
        int e = cs + i * 256 + tid;
        if (e < ne) {
            int b = dst[e] >> BSH;
            int r = atomicAdd(&hist[b], 1);      // rank within (block,bucket)
            pack[i] = (unsigned)((b << 13) | r); // b<=781 (10b), r<8192 (13b)
        } else {
            pack[i] = 0xFFFFFFFFu;
        }
    }
    __syncthreads();
    for (int b = tid; b < NBUK; b += 256) {
        int c = hist[b];
        base[b] = c ? atomicAdd(&bcursor[b], c) : 0;
    }
    __syncthreads();
#pragma unroll 8
    for (int i = 0; i < SC_CHUNK / 256; ++i) {
        if (pack[i] != 0xFFFFFFFFu) {
            int e = cs + i * 256 + tid;
            int b = pack[i] >> 13, r = pack[i] & 8191;
            E2[base[b] + r] = make_int2(src[e], dst[e]);
        }
    }
}

// ---------------- per-bucket CSR build ----------------

__global__ __launch_bounds__(256) void k_csrb(const int2* __restrict__ E2,
                                              const int* __restrict__ bbase,
                                              int* __restrict__ rowptr,
                                              int* __restrict__ col, int n) {
    __shared__ int cnt[BNODES];
    __shared__ int pref[BNODES];
    const int tid = threadIdx.x;
    const int bs = bbase[blockIdx.x], be = bbase[blockIdx.x + 1];
    for (int i = tid; i < BNODES; i += 256) cnt[i] = 0;
    __syncthreads();
    for (int e = bs + tid; e < be; e += 256)
        atomicAdd(&cnt[E2[e].y & (BNODES - 1)], 1);
    __syncthreads();
    if (tid < 64) { // wave 0 scans 128 counts, 2/lane (wave-uniform branch)
        int c0 = cnt[tid * 2], c1 = cnt[tid * 2 + 1];
        int s = c0 + c1;
        int x = s;
#pragma unroll
        for (int off = 1; off < 64; off <<= 1) {
            int y = __shfl_up(x, off, 64);
            if (tid >= off) x += y;
        }
        int ex = x - s; // exclusive
        pref[tid * 2] = ex;
        pref[tid * 2 + 1] = ex + c0;
    }
    __syncthreads();
    const int nodeBase = blockIdx.x * BNODES;
    for (int i = tid; i < BNODES; i += 256) {
        int gn = nodeBase + i;
        if (gn < n) rowptr[gn] = bs + pref[i];
        cnt[i] = 0; // reuse as cursor
    }
    __syncthreads();
    for (int e = bs + tid; e < be; e += 256) {
        int2 pr = E2[e];
        int d = pr.y & (BNODES - 1);
        int r = atomicAdd(&cnt[d], 1);
        col[bs + pref[d] + r] = pr.x;
    }
    if (blockIdx.x == 0 && tid == 0) rowptr[n] = bbase[NBUK];
}

// ---------------- fused dual linear: Y = X@Wl, R = X@Wr ----------------
// Scalar-W GEMM, v3. 256 threads = 4 waves; block owns 128 nodes; each lane
// handles nodes (lane) and (lane+64) -> each wave-uniform W-row s_load now
// feeds 64 FMAs (r7: 32 -> load-latency chain dominated, VALUBusy 24%).
// wv from readfirstlane keeps the W pointer provably SGPR-uniform (s_load
// on the otherwise-idle SMEM pipe; LDS carries only X, conflict-free).
// Inner loops have COMPILE-TIME trip counts (KC=64 full chunks + K%64
// tail) so the compiler can unroll and batch s_loads rows ahead.

template <int K>
__global__ __launch_bounds__(256) void k_linear(const float* __restrict__ X,
                                                const float* __restrict__ Wl,
                                                const float* __restrict__ Wr,
                                                float* __restrict__ Y,
                                                float* __restrict__ R, int n) {
    constexpr int KC = 64;
    constexpr int LDR = KC + 1;   // 65: (lane+kk)%32 -> 2-way alias, free
    constexpr int NFULL = K / KC;
    constexpr int TAIL = K % KC;
    __shared__ float Xs[128 * LDR]; // 33.3 KB

    const int tid = threadIdx.x;
    const int lane = tid & 63;
    const int wv = __builtin_amdgcn_readfirstlane(tid >> 6);   // UNIFORM
    const float* __restrict__ W = (wv & 2) ? Wr : Wl;
    const int cb = (wv & 1) * 32;
    const int nodeBase = blockIdx.x * 128;

    float acc0[32], acc1[32];
#pragma unroll
    for (int t = 0; t < 32; ++t) { acc0[t] = 0.f; acc1[t] = 0.f; }

    // stage: e -> k = e&63 (consec lanes = consec k: coalesced 256B), m = e>>6
    auto stage = [&](int c, int kw) {
        __syncthreads();
#pragma unroll
        for (int i = 0; i < 32; ++i) {
            int e = tid + i * 256;
            int k = e & 63;
            int m = e >> 6;
            if (k < kw) {
                int gn = nodeBase + m;
                if (gn >= n) gn = n - 1;
                Xs[m * LDR + k] = X[(size_t)gn * K + c + k];
            }
        }
        __syncthreads();
    };
    auto body = [&](int c, int kk) {
        const float xv0 = Xs[lane * LDR + kk];
        const float xv1 = Xs[(lane + 64) * LDR + kk];
        const float* __restrict__ wrow = W + (size_t)(c + kk) * HID + cb;
#pragma unroll
        for (int t = 0; t < 32; ++t) {
            const float w = wrow[t];
            acc0[t] = fmaf(xv0, w, acc0[t]);
            acc1[t] = fmaf(xv1, w, acc1[t]);
        }
    };

    for (int ch = 0; ch < NFULL; ++ch) {
        const int c = ch * KC;
        stage(c, KC);
#pragma unroll 8
        for (int kk = 0; kk < KC; ++kk) body(c, kk);
    }
    if (TAIL) {
        const int c = NFULL * KC;
        stage(c, TAIL);
#pragma unroll 8
        for (int kk = 0; kk < TAIL; ++kk) body(c, kk);
    }

    // epilogue: each lane owns two contiguous 128 B half-rows
    float* __restrict__ dbuf = (wv & 2) ? R : Y;
    const int gn0 = nodeBase + lane;
    const int gn1 = nodeBase + 64 + lane;
    if (gn0 < n) {
#pragma unroll
        for (int q = 0; q < 8; ++q)
            *(float4*)&dbuf[(size_t)gn0 * HID + cb + q * 4] =
                make_float4(acc0[q * 4], acc0[q * 4 + 1], acc0[q * 4 + 2], acc0[q * 4 + 3]);
    }
    if (gn1 < n) {
#pragma unroll
        for (int q = 0; q < 8; ++q)
            *(float4*)&dbuf[(size_t)gn1 * HID + cb + q * 4] =
                make_float4(acc1[q * 4], acc1[q * 4 + 1], acc1[q * 4 + 2], acc1[q * 4 + 3]);
    }
}

// ---------------- aggregation (+ optional fused classifier) ----------------
// Wave per node, float2 per lane: lanes 0-31 process edge i, lanes 32-63
// edge i+1; halves merged with shfl_xor(32); redistribute shuffles kept in
// uniform control flow (EXEC-gated ds_bpermute — round-5 bug).

template <bool CLS>
__global__ __launch_bounds__(256) void k_agg(const float* __restrict__ Y,
                                             const float* __restrict__ Rm,
                                             const float* __restrict__ bias,
                                             const int* __restrict__ rowptr,
                                             const int* __restrict__ col,
                                             float* __restrict__ H,
                                             const float* __restrict__ Wc,
                                             const float* __restrict__ bc,
                                             float* __restrict__ out, int n) {
    const int lane = threadIdx.x & 63;
    const int node = blockIdx.x * 4 + (threadIdx.x >> 6);
    if (node >= n) return;
    const int half = lane >> 5;        // which edge of the pair
    const int fl = (lane & 31) * 2;    // feature pair
    const int s = rowptr[node], e = rowptr[node + 1];
    float ax = 0.f, ay = 0.f;
    int i = s + half;
    for (; i + 6 < e; i += 8) {
        int s0 = col[i], s1 = col[i + 2], s2 = col[i + 4], s3 = col[i + 6];
        float2 y0 = *(const float2*)&Y[(size_t)s0 * HID + fl];
        float2 y1 = *(const float2*)&Y[(size_t)s1 * HID + fl];
        float2 y2 = *(const float2*)&Y[(size_t)s2 * HID + fl];
        float2 y3 = *(const float2*)&Y[(size_t)s3 * HID + fl];
        ax += (y0.x + y1.x) + (y2.x + y3.x);
        ay += (y0.y + y1.y) + (y2.y + y3.y);
    }
    for (; i < e; i += 2) {
        float2 yv = *(const float2*)&Y[(size_t)col[i] * HID + fl];
        ax += yv.x;
        ay += yv.y;
    }
    ax += __shfl_xor(ax, 32, 64);
    ay += __shfl_xor(ay, 32, 64);
    const float vx = __shfl(ax, lane >> 1, 64);
    const float vy = __shfl(ay, lane >> 1, 64);
    const float acc = (lane & 1) ? vy : vx;
    const int deg = e - s;
    float h = acc / (float)(deg > 1 ? deg : 1) + bias[lane] + Rm[(size_t)node * HID + lane];
    h = fmaxf(h, 0.f);
    if (!CLS) {
        H[(size_t)node * HID + lane] = h;
    } else {
        float p0 = h * Wc[lane * 2 + 0];
        float p1 = h * Wc[lane * 2 + 1];
#pragma unroll
        for (int off = 32; off > 0; off >>= 1) {
            p0 += __shfl_xor(p0, off, 64);
            p1 += __shfl_xor(p1, off, 64);
        }
        if (lane == 0) {
            out[(size_t)node * 2 + 0] = p0 + bc[0];
            out[(size_t)node * 2 + 1] = p1 + bc[1];
        }
    }
}

// ---------------- launch ----------------

extern "C" void kernel_launch(void* const* d_in, const int* in_sizes, int n_in,
                              void* d_out, int out_size, void* d_ws, size_t ws_size,
                              hipStream_t stream) {
    const float* x   = (const float*)d_in[0];
    const int*   ei  = (const int*)d_in[1];
    const float* W1l = (const float*)d_in[2];
    const float* b1  = (const float*)d_in[3];
    const float* W1r = (const float*)d_in[4];
    const float* W2l = (const float*)d_in[5];
    const float* b2  = (const float*)d_in[6];
    const float* W2r = (const float*)d_in[7];
    const float* Wc  = (const float*)d_in[8];
    const float* bc  = (const float*)d_in[9];
    float* out = (float*)d_out;
    const int* src = ei;
    const int* dst = ei + NE;

    char* base = (char*)d_ws;
    size_t off = 0;
    auto alloc = [&](size_t bytes) {
        void* p = base + off;
        off = (off + bytes + 255) & ~(size_t)255;
        return p;
    };
    int*   bhist   = (int*)alloc((size_t)NBUK * 4);
    int*   bbase   = (int*)alloc((size_t)(NBUK + 1) * 4);
    int*   bcursor = (int*)alloc((size_t)NBUK * 4);
    int*   rowptr  = (int*)alloc((size_t)(NN + 1) * 4);
    int*   col     = (int*)alloc((size_t)NE * 4);
    // E2 (12.8 MB) is dead after k_csrb -> alias it under Y (25.6 MB)
    float* Y       = (float*)alloc((size_t)NN * HID * 4);
    float* R       = (float*)alloc((size_t)NN * HID * 4);
    float* H1      = (float*)alloc((size_t)NN * HID * 4);
    int2*  E2      = (int2*)Y;

    const int sb = (NE + SC_CHUNK - 1) / SC_CHUNK; // 196

    hipMemsetAsync(bhist, 0, (size_t)NBUK * 4, stream);
    k_bhist<<<sb, 256, 0, stream>>>(dst, bhist, NE);
    k_bscan<<<1, 256, 0, stream>>>(bhist, bbase, bcursor);
    k_scatter<<<sb, 256, 0, stream>>>(src, dst, bcursor, E2, NE);
    k_csrb<<<NBUK, 256, 0, stream>>>(E2, bbase, rowptr, col, NN);

    k_linear<INDIM><<<(NN + 127) / 128, 256, 0, stream>>>(x, W1l, W1r, Y, R, NN);
    k_agg<false><<<(NN + 3) / 4, 256, 0, stream>>>(Y, R, b1, rowptr, col, H1,
                                                   nullptr, nullptr, nullptr, NN);
    k_linear<HID><<<(NN + 127) / 128, 256, 0, stream>>>(H1, W2l, W2r, Y, R, NN);
    k_agg<true><<<(NN + 3) / 4, 256, 0, stream>>>(Y, R, b2, rowptr, col, nullptr,
                                                  Wc, bc, out, NN);
}

// Round 9
// 419.590 us; speedup vs baseline: 1.3348x; 1.3348x over previous
//
#include <hip/hip_runtime.h>
#include <cstdint>

#define NN 100000
#define NE 1600000
#define INDIM 165
#define HID 64

// dst-bucket partition: bucket = dst >> BSH, BNODES nodes per bucket
constexpr int BSH = 7;
constexpr int BNODES = 128;               // 1 << BSH
constexpr int NBUK = (NN + BNODES - 1) / BNODES; // 782
constexpr int SC_CHUNK = 8192;            // edges per scatter block

// ---------------- bucket histogram ----------------

__global__ __launch_bounds__(256) void k_bhist(const int* __restrict__ dst,
                                               int* __restrict__ bhist, int ne) {
    __shared__ int h[NBUK];
    for (int b = threadIdx.x; b < NBUK; b += 256) h[b] = 0;
    __syncthreads();
    for (int e = blockIdx.x * blockDim.x + threadIdx.x; e < ne;
         e += gridDim.x * blockDim.x)
        atomicAdd(&h[dst[e] >> BSH], 1);
    __syncthreads();
    for (int b = threadIdx.x; b < NBUK; b += 256)
        if (h[b]) atomicAdd(&bhist[b], h[b]);
}

// ---------------- scan of 782 bucket counts (single block) ----------------

__global__ __launch_bounds__(256) void k_bscan(const int* __restrict__ bhist,
                                               int* __restrict__ bbase,
                                               int* __restrict__ bcursor) {
    __shared__ int wsum[4];
    const int tid = threadIdx.x, lane = tid & 63, wid = tid >> 6;
    int v[4];
    int tsum = 0;
#pragma unroll
    for (int i = 0; i < 4; ++i) {
        int idx = tid * 4 + i;
        v[i] = (idx < NBUK) ? bhist[idx] : 0;
        tsum += v[i];
    }
    int x = tsum;
#pragma unroll
    for (int off = 1; off < 64; off <<= 1) {
        int y = __shfl_up(x, off, 64);
        if (lane >= off) x += y;
    }
    if (lane == 63) wsum[wid] = x;
    __syncthreads();
    int woff = 0;
#pragma unroll
    for (int w = 0; w < 4; ++w)
        if (w < wid) woff += wsum[w];
    int run = woff + x - tsum;
#pragma unroll
    for (int i = 0; i < 4; ++i) {
        int idx = tid * 4 + i;
        if (idx < NBUK) { bbase[idx] = run; bcursor[idx] = run; }
        run += v[i];
    }
    if (tid == 255) bbase[NBUK] = woff + x; // grand total (= ne)
}

// ---------------- partition edges into bucket-major (src,dst) pairs --------

__global__ __launch_bounds__(256) void k_scatter(const int* __restrict__ src,
                                                 const int* __restrict__ dst,
                                                 int* __restrict__ bcursor,
                                                 int2* __restrict__ E2, int ne) {
    __shared__ int hist[NBUK];
    __shared__ int base[NBUK];
    const int tid = threadIdx.x;
    const int cs = blockIdx.x * SC_CHUNK;
    for (int b = tid; b < NBUK; b += 256) hist[b] = 0;
    __syncthreads();
    unsigned pack[SC_CHUNK / 256];
#pragma unroll 8
    for (int i = 0; i < SC_CHUNK / 256; ++i) {
        int e = cs + i * 256 + tid;
        if (e < ne) {
            int b = dst[e] >> BSH;
            int r = atomicAdd(&hist[b], 1);      // rank within (block,bucket)
            pack[i] = (unsigned)((b << 13) | r); // b<=781 (10b), r<8192 (13b)
        } else {
            pack[i] = 0xFFFFFFFFu;
        }
    }
    __syncthreads();
    for (int b = tid; b < NBUK; b += 256) {
        int c = hist[b];
        base[b] = c ? atomicAdd(&bcursor[b], c) : 0;
    }
    __syncthreads();
#pragma unroll 8
    for (int i = 0; i < SC_CHUNK / 256; ++i) {
        if (pack[i] != 0xFFFFFFFFu) {
            int e = cs + i * 256 + tid;
            int b = pack[i] >> 13, r = pack[i] & 8191;
            E2[base[b] + r] = make_int2(src[e], dst[e]);
        }
    }
}

// ---------------- per-bucket CSR build ----------------

__global__ __launch_bounds__(256) void k_csrb(const int2* __restrict__ E2,
                                              const int* __restrict__ bbase,
                                              int* __restrict__ rowptr,
                                              int* __restrict__ col, int n) {
    __shared__ int cnt[BNODES];
    __shared__ int pref[BNODES];
    const int tid = threadIdx.x;
    const int bs = bbase[blockIdx.x], be = bbase[blockIdx.x + 1];
    for (int i = tid; i < BNODES; i += 256) cnt[i] = 0;
    __syncthreads();
    for (int e = bs + tid; e < be; e += 256)
        atomicAdd(&cnt[E2[e].y & (BNODES - 1)], 1);
    __syncthreads();
    if (tid < 64) { // wave 0 scans 128 counts, 2/lane (wave-uniform branch)
        int c0 = cnt[tid * 2], c1 = cnt[tid * 2 + 1];
        int s = c0 + c1;
        int x = s;
#pragma unroll
        for (int off = 1; off < 64; off <<= 1) {
            int y = __shfl_up(x, off, 64);
            if (tid >= off) x += y;
        }
        int ex = x - s; // exclusive
        pref[tid * 2] = ex;
        pref[tid * 2 + 1] = ex + c0;
    }
    __syncthreads();
    const int nodeBase = blockIdx.x * BNODES;
    for (int i = tid; i < BNODES; i += 256) {
        int gn = nodeBase + i;
        if (gn < n) rowptr[gn] = bs + pref[i];
        cnt[i] = 0; // reuse as cursor
    }
    __syncthreads();
    for (int e = bs + tid; e < be; e += 256) {
        int2 pr = E2[e];
        int d = pr.y & (BNODES - 1);
        int r = atomicAdd(&cnt[d], 1);
        col[bs + pref[d] + r] = pr.x;
    }
    if (blockIdx.x == 0 && tid == 0) rowptr[n] = bbase[NBUK];
}

// ---------------- fused dual linear: Y = X@Wl, R = X@Wr ----------------
// Round-6 register-tiled GEMM (best measured: ~100 us) + W bank-conflict
// fix. [M x K] @ [K x 128] (cols 0..63 = Wl, 64..127 = Wr), 256 threads,
// tile 128x128, K-chunk 32, 8x8 microtile (4 ds_read_b128 + 64 v_fma/kk).
//
// Bank analysis (r6 measured 6.6M SQ_LDS_BANK_CONFLICT): X reads have only
// 4 distinct addrs/instr (16-lane broadcast) -> conflict-free. W reads had
// 16 float4s at 32-float stride -> bank starts only {0,8,16,24} -> 4-way.
// Fix: SPLIT layout. Column block b (8 floats) stored as lo half at float
// offset 4b and hi half at 64+4b (row stride 128). wa addrs {0,4,..,60},
// wb {64,..,124}: bank starts cover all 8 groups evenly -> 2-way broadcast
// = free (m136). Staging writes become 4-way but are 64x rarer than reads.

template <int K>
__global__ __launch_bounds__(256) void k_linear(const float* __restrict__ X,
                                                const float* __restrict__ Wl,
                                                const float* __restrict__ Wr,
                                                float* __restrict__ Y,
                                                float* __restrict__ R, int n) {
    constexpr int KC = 32;
    constexpr int MT = 128;
    constexpr int LDX = 132; // +4 pad: bank (k+m)%32 -> conflict-free staging
    __shared__ float Xs[KC][LDX]; // Xs[k][m]
    __shared__ float Ws[KC][128]; // split lo/hi layout (see above)

    const int tid = threadIdx.x;
    const int m0 = (tid >> 4) * 8;
    const int n0 = (tid & 15) * 8;
    const int nodeBase = blockIdx.x * MT;

    float acc[8][8];
#pragma unroll
    for (int i = 0; i < 8; ++i)
#pragma unroll
        for (int j = 0; j < 8; ++j) acc[i][j] = 0.f;

    for (int c = 0; c < K; c += KC) {
        const int kw = (K - c < KC) ? (K - c) : KC;
        __syncthreads();
        // stage X: e -> k = e&31 (consec lanes = consec k: coalesced), m = e>>5
#pragma unroll
        for (int i = 0; i < 16; ++i) {
            int e = tid + i * 256;
            int k = e & 31;
            int m = e >> 5;
            int gn = nodeBase + m;
            if (gn >= n) gn = n - 1;
            Xs[k][m] = (k < kw) ? X[(size_t)gn * K + c + k] : 0.f;
        }
        // stage W: logical float4 col nf -> split position
#pragma unroll
        for (int i = 0; i < 4; ++i) {
            int v = tid + i * 256;
            int k = v >> 5;
            int nf = (v & 31) * 4;
            float4 w;
            if (k < kw) {
                const float* sp = (nf < 64) ? (Wl + (size_t)(c + k) * HID + nf)
                                            : (Wr + (size_t)(c + k) * HID + (nf - 64));
                w = *(const float4*)sp;
            } else {
                w = make_float4(0.f, 0.f, 0.f, 0.f);
            }
            const int pos = ((nf >> 2) & 1) * 64 + (nf >> 3) * 4;
            *(float4*)&Ws[k][pos] = w;
        }
        __syncthreads();
#pragma unroll 4
        for (int kk = 0; kk < KC; ++kk) {
            const float4 xa = *(const float4*)&Xs[kk][m0];
            const float4 xb = *(const float4*)&Xs[kk][m0 + 4];
            const float4 wa = *(const float4*)&Ws[kk][n0 >> 1];        // lo
            const float4 wb = *(const float4*)&Ws[kk][64 + (n0 >> 1)]; // hi
            const float xm[8] = {xa.x, xa.y, xa.z, xa.w, xb.x, xb.y, xb.z, xb.w};
            const float wn[8] = {wa.x, wa.y, wa.z, wa.w, wb.x, wb.y, wb.z, wb.w};
#pragma unroll
            for (int i = 0; i < 8; ++i)
#pragma unroll
                for (int j = 0; j < 8; ++j)
                    acc[i][j] = fmaf(xm[i], wn[j], acc[i][j]);
        }
    }

    // epilogue: n0<64 -> Y, else -> R; coalesced float4 row stores
    float* __restrict__ dbuf = (n0 < HID) ? Y : R;
    const int nc = n0 & (HID - 1);
#pragma unroll
    for (int i = 0; i < 8; ++i) {
        const int gn = nodeBase + m0 + i;
        if (gn < n) {
            float4 lo = make_float4(acc[i][0], acc[i][1], acc[i][2], acc[i][3]);
            float4 hi = make_float4(acc[i][4], acc[i][5], acc[i][6], acc[i][7]);
            *(float4*)&dbuf[(size_t)gn * HID + nc] = lo;
            *(float4*)&dbuf[(size_t)gn * HID + nc + 4] = hi;
        }
    }
}

// ---------------- aggregation (+ optional fused classifier) ----------------
// Wave per node, float2 per lane: lanes 0-31 process edge i, lanes 32-63
// edge i+1; halves merged with shfl_xor(32); redistribute shuffles kept in
// uniform control flow (EXEC-gated ds_bpermute — round-5 bug).

template <bool CLS>
__global__ __launch_bounds__(256) void k_agg(const float* __restrict__ Y,
                                             const float* __restrict__ Rm,
                                             const float* __restrict__ bias,
                                             const int* __restrict__ rowptr,
                                             const int* __restrict__ col,
                                             float* __restrict__ H,
                                             const float* __restrict__ Wc,
                                             const float* __restrict__ bc,
                                             float* __restrict__ out, int n) {
    const int lane = threadIdx.x & 63;
    const int node = blockIdx.x * 4 + (threadIdx.x >> 6);
    if (node >= n) return;
    const int half = lane >> 5;        // which edge of the pair
    const int fl = (lane & 31) * 2;    // feature pair
    const int s = rowptr[node], e = rowptr[node + 1];
    float ax = 0.f, ay = 0.f;
    int i = s + half;
    for (; i + 6 < e; i += 8) {
        int s0 = col[i], s1 = col[i + 2], s2 = col[i + 4], s3 = col[i + 6];
        float2 y0 = *(const float2*)&Y[(size_t)s0 * HID + fl];
        float2 y1 = *(const float2*)&Y[(size_t)s1 * HID + fl];
        float2 y2 = *(const float2*)&Y[(size_t)s2 * HID + fl];
        float2 y3 = *(const float2*)&Y[(size_t)s3 * HID + fl];
        ax += (y0.x + y1.x) + (y2.x + y3.x);
        ay += (y0.y + y1.y) + (y2.y + y3.y);
    }
    for (; i < e; i += 2) {
        float2 yv = *(const float2*)&Y[(size_t)col[i] * HID + fl];
        ax += yv.x;
        ay += yv.y;
    }
    ax += __shfl_xor(ax, 32, 64);
    ay += __shfl_xor(ay, 32, 64);
    const float vx = __shfl(ax, lane >> 1, 64);
    const float vy = __shfl(ay, lane >> 1, 64);
    const float acc = (lane & 1) ? vy : vx;
    const int deg = e - s;
    float h = acc / (float)(deg > 1 ? deg : 1) + bias[lane] + Rm[(size_t)node * HID + lane];
    h = fmaxf(h, 0.f);
    if (!CLS) {
        H[(size_t)node * HID + lane] = h;
    } else {
        float p0 = h * Wc[lane * 2 + 0];
        float p1 = h * Wc[lane * 2 + 1];
#pragma unroll
        for (int off = 32; off > 0; off >>= 1) {
            p0 += __shfl_xor(p0, off, 64);
            p1 += __shfl_xor(p1, off, 64);
        }
        if (lane == 0) {
            out[(size_t)node * 2 + 0] = p0 + bc[0];
            out[(size_t)node * 2 + 1] = p1 + bc[1];
        }
    }
}

// ---------------- launch ----------------

extern "C" void kernel_launch(void* const* d_in, const int* in_sizes, int n_in,
                              void* d_out, int out_size, void* d_ws, size_t ws_size,
                              hipStream_t stream) {
    const float* x   = (const float*)d_in[0];
    const int*   ei  = (const int*)d_in[1];
    const float* W1l = (const float*)d_in[2];
    const float* b1  = (const float*)d_in[3];
    const float* W1r = (const float*)d_in[4];
    const float* W2l = (const float*)d_in[5];
    const float* b2  = (const float*)d_in[6];
    const float* W2r = (const float*)d_in[7];
    const float* Wc  = (const float*)d_in[8];
    const float* bc  = (const float*)d_in[9];
    float* out = (float*)d_out;
    const int* src = ei;
    const int* dst = ei + NE;

    char* base = (char*)d_ws;
    size_t off = 0;
    auto alloc = [&](size_t bytes) {
        void* p = base + off;
        off = (off + bytes + 255) & ~(size_t)255;
        return p;
    };
    int*   bhist   = (int*)alloc((size_t)NBUK * 4);
    int*   bbase   = (int*)alloc((size_t)(NBUK + 1) * 4);
    int*   bcursor = (int*)alloc((size_t)NBUK * 4);
    int*   rowptr  = (int*)alloc((size_t)(NN + 1) * 4);
    int*   col     = (int*)alloc((size_t)NE * 4);
    // E2 (12.8 MB) is dead after k_csrb -> alias it under Y (25.6 MB)
    float* Y       = (float*)alloc((size_t)NN * HID * 4);
    float* R       = (float*)alloc((size_t)NN * HID * 4);
    float* H1      = (float*)alloc((size_t)NN * HID * 4);
    int2*  E2      = (int2*)Y;

    const int sb = (NE + SC_CHUNK - 1) / SC_CHUNK; // 196

    hipMemsetAsync(bhist, 0, (size_t)NBUK * 4, stream);
    k_bhist<<<sb, 256, 0, stream>>>(dst, bhist, NE);
    k_bscan<<<1, 256, 0, stream>>>(bhist, bbase, bcursor);
    k_scatter<<<sb, 256, 0, stream>>>(src, dst, bcursor, E2, NE);
    k_csrb<<<NBUK, 256, 0, stream>>>(E2, bbase, rowptr, col, NN);

    k_linear<INDIM><<<(NN + 127) / 128, 256, 0, stream>>>(x, W1l, W1r, Y, R, NN);
    k_agg<false><<<(NN + 3) / 4, 256, 0, stream>>>(Y, R, b1, rowptr, col, H1,
                                                   nullptr, nullptr, nullptr, NN);
    k_linear<HID><<<(NN + 127) / 128, 256, 0, stream>>>(H1, W2l, W2r, Y, R, NN);
    k_agg<true><<<(NN + 3) / 4, 256, 0, stream>>>(Y, R, b2, rowptr, col, nullptr,
                                                  Wc, bc, out, NN);
}

// Round 10
// 416.695 us; speedup vs baseline: 1.3441x; 1.0069x over previous
//
#include <hip/hip_runtime.h>
#include <cstdint>

#define NN 100000
#define NE 1600000
#define INDIM 165
#define HID 64

// dst-bucket partition: bucket = dst >> BSH, BNODES nodes per bucket
constexpr int BSH = 7;
constexpr int BNODES = 128;               // 1 << BSH
constexpr int NBUK = (NN + BNODES - 1) / BNODES; // 782
constexpr int SC_CHUNK = 8192;            // edges per scatter block

// ---------------- bucket histogram ----------------

__global__ __launch_bounds__(256) void k_bhist(const int* __restrict__ dst,
                                               int* __restrict__ bhist, int ne) {
    __shared__ int h[NBUK];
    for (int b = threadIdx.x; b < NBUK; b += 256) h[b] = 0;
    __syncthreads();
    for (int e = blockIdx.x * blockDim.x + threadIdx.x; e < ne;
         e += gridDim.x * blockDim.x)
        atomicAdd(&h[dst[e] >> BSH], 1);
    __syncthreads();
    for (int b = threadIdx.x; b < NBUK; b += 256)
        if (h[b]) atomicAdd(&bhist[b], h[b]);
}

// ---------------- scan of 782 bucket counts (single block) ----------------

__global__ __launch_bounds__(256) void k_bscan(const int* __restrict__ bhist,
                                               int* __restrict__ bbase,
                                               int* __restrict__ bcursor) {
    __shared__ int wsum[4];
    const int tid = threadIdx.x, lane = tid & 63, wid = tid >> 6;
    int v[4];
    int tsum = 0;
#pragma unroll
    for (int i = 0; i < 4; ++i) {
        int idx = tid * 4 + i;
        v[i] = (idx < NBUK) ? bhist[idx] : 0;
        tsum += v[i];
    }
    int x = tsum;
#pragma unroll
    for (int off = 1; off < 64; off <<= 1) {
        int y = __shfl_up(x, off, 64);
        if (lane >= off) x += y;
    }
    if (lane == 63) wsum[wid] = x;
    __syncthreads();
    int woff = 0;
#pragma unroll
    for (int w = 0; w < 4; ++w)
        if (w < wid) woff += wsum[w];
    int run = woff + x - tsum;
#pragma unroll
    for (int i = 0; i < 4; ++i) {
        int idx = tid * 4 + i;
        if (idx < NBUK) { bbase[idx] = run; bcursor[idx] = run; }
        run += v[i];
    }
    if (tid == 255) bbase[NBUK] = woff + x; // grand total (= ne)
}

// ---------------- partition edges into bucket-major (src,dst) pairs --------

__global__ __launch_bounds__(256) void k_scatter(const int* __restrict__ src,
                                                 const int* __restrict__ dst,
                                                 int* __restrict__ bcursor,
                                                 int2* __restrict__ E2, int ne) {
    __shared__ int hist[NBUK];
    __shared__ int base[NBUK];
    const int tid = threadIdx.x;
    const int cs = blockIdx.x * SC_CHUNK;
    for (int b = tid; b < NBUK; b += 256) hist[b] = 0;
    __syncthreads();
    unsigned pack[SC_CHUNK / 256];
#pragma unroll 8
    for (int i = 0; i < SC_CHUNK / 256; ++i) {
        int e = cs + i * 256 + tid;
        if (e < ne) {
            int b = dst[e] >> BSH;
            int r = atomicAdd(&hist[b], 1);      // rank within (block,bucket)
            pack[i] = (unsigned)((b << 13) | r); // b<=781 (10b), r<8192 (13b)
        } else {
            pack[i] = 0xFFFFFFFFu;
        }
    }
    __syncthreads();
    for (int b = tid; b < NBUK; b += 256) {
        int c = hist[b];
        base[b] = c ? atomicAdd(&bcursor[b], c) : 0;
    }
    __syncthreads();
#pragma unroll 8
    for (int i = 0; i < SC_CHUNK / 256; ++i) {
        if (pack[i] != 0xFFFFFFFFu) {
            int e = cs + i * 256 + tid;
            int b = pack[i] >> 13, r = pack[i] & 8191;
            E2[base[b] + r] = make_int2(src[e], dst[e]);
        }
    }
}

// ---------------- per-bucket CSR build ----------------

__global__ __launch_bounds__(256) void k_csrb(const int2* __restrict__ E2,
                                              const int* __restrict__ bbase,
                                              int* __restrict__ rowptr,
                                              int* __restrict__ col, int n) {
    __shared__ int cnt[BNODES];
    __shared__ int pref[BNODES];
    const int tid = threadIdx.x;
    const int bs = bbase[blockIdx.x], be = bbase[blockIdx.x + 1];
    for (int i = tid; i < BNODES; i += 256) cnt[i] = 0;
    __syncthreads();
    for (int e = bs + tid; e < be; e += 256)
        atomicAdd(&cnt[E2[e].y & (BNODES - 1)], 1);
    __syncthreads();
    if (tid < 64) { // wave 0 scans 128 counts, 2/lane (wave-uniform branch)
        int c0 = cnt[tid * 2], c1 = cnt[tid * 2 + 1];
        int s = c0 + c1;
        int x = s;
#pragma unroll
        for (int off = 1; off < 64; off <<= 1) {
            int y = __shfl_up(x, off, 64);
            if (tid >= off) x += y;
        }
        int ex = x - s; // exclusive
        pref[tid * 2] = ex;
        pref[tid * 2 + 1] = ex + c0;
    }
    __syncthreads();
    const int nodeBase = blockIdx.x * BNODES;
    for (int i = tid; i < BNODES; i += 256) {
        int gn = nodeBase + i;
        if (gn < n) rowptr[gn] = bs + pref[i];
        cnt[i] = 0; // reuse as cursor
    }
    __syncthreads();
    for (int e = bs + tid; e < be; e += 256) {
        int2 pr = E2[e];
        int d = pr.y & (BNODES - 1);
        int r = atomicAdd(&cnt[d], 1);
        col[bs + pref[d] + r] = pr.x;
    }
    if (blockIdx.x == 0 && tid == 0) rowptr[n] = bbase[NBUK];
}

// ---------------- fused dual linear: Y = X@Wl, R = X@Wr ----------------
// Register-tiled GEMM + REGISTER-PREFETCH PIPELINE. r9 showed the 2-barrier
// K-loop is the limit (conflicts fixed, dur unchanged, VALUBusy 38%,
// occupancy 19%): every chunk serialized global-load latency (~900 cyc)
// behind vmcnt(0)+barrier. Now chunk ch+1's X/W are loaded into registers
// DURING chunk ch's compute (4096 cyc/wave) and dumped to LDS after the
// barrier -> the vmcnt wait lands after compute, latency hidden.
// Layouts unchanged from r9: Xs stride 132 (conflict-free), Ws split lo/hi
// (2-way broadcast only, free per m136).

template <int K>
__global__ __launch_bounds__(256) void k_linear(const float* __restrict__ X,
                                                const float* __restrict__ Wl,
                                                const float* __restrict__ Wr,
                                                float* __restrict__ Y,
                                                float* __restrict__ R, int n) {
    constexpr int KC = 32;
    constexpr int MT = 128;
    constexpr int LDX = 132;
    constexpr int NCH = (K + KC - 1) / KC;
    __shared__ float Xs[KC][LDX]; // Xs[k][m]
    __shared__ float Ws[KC][128]; // split lo/hi layout

    const int tid = threadIdx.x;
    const int m0 = (tid >> 4) * 8;
    const int n0 = (tid & 15) * 8;
    const int nodeBase = blockIdx.x * MT;

    float acc[8][8];
#pragma unroll
    for (int i = 0; i < 8; ++i)
#pragma unroll
        for (int j = 0; j < 8; ++j) acc[i][j] = 0.f;

    float  xr[16];
    float4 wr[4];

    auto prefetch = [&](int c) {
        // X: e -> k = e&31 (consec lanes = consec k: coalesced), m = e>>5
#pragma unroll
        for (int i = 0; i < 16; ++i) {
            int e = tid + i * 256;
            int k = e & 31;
            int m = e >> 5;
            int gn = nodeBase + m;
            if (gn >= n) gn = n - 1;
            xr[i] = (c + k < K) ? X[(size_t)gn * K + c + k] : 0.f;
        }
        // W rows (coalesced float4)
#pragma unroll
        for (int i = 0; i < 4; ++i) {
            int v = tid + i * 256;
            int k = v >> 5;
            int nf = (v & 31) * 4;
            if (c + k < K) {
                const float* sp = (nf < 64) ? (Wl + (size_t)(c + k) * HID + nf)
                                            : (Wr + (size_t)(c + k) * HID + (nf - 64));
                wr[i] = *(const float4*)sp;
            } else {
                wr[i] = make_float4(0.f, 0.f, 0.f, 0.f);
            }
        }
    };
    auto commit = [&]() {
#pragma unroll
        for (int i = 0; i < 16; ++i) {
            int e = tid + i * 256;
            Xs[e & 31][e >> 5] = xr[i];
        }
#pragma unroll
        for (int i = 0; i < 4; ++i) {
            int v = tid + i * 256;
            int k = v >> 5;
            int nf = (v & 31) * 4;
            const int pos = ((nf >> 2) & 1) * 64 + (nf >> 3) * 4;
            *(float4*)&Ws[k][pos] = wr[i];
        }
    };

    prefetch(0);
    commit();
    for (int ch = 0; ch < NCH; ++ch) {
        __syncthreads(); // LDS chunk ch visible to all waves
        if (ch + 1 < NCH) prefetch((ch + 1) * KC); // loads fly during compute
#pragma unroll 4
        for (int kk = 0; kk < KC; ++kk) {
            const float4 xa = *(const float4*)&Xs[kk][m0];
            const float4 xb = *(const float4*)&Xs[kk][m0 + 4];
            const float4 wa = *(const float4*)&Ws[kk][n0 >> 1];        // lo
            const float4 wb = *(const float4*)&Ws[kk][64 + (n0 >> 1)]; // hi
            const float xm[8] = {xa.x, xa.y, xa.z, xa.w, xb.x, xb.y, xb.z, xb.w};
            const float wn[8] = {wa.x, wa.y, wa.z, wa.w, wb.x, wb.y, wb.z, wb.w};
#pragma unroll
            for (int i = 0; i < 8; ++i)
#pragma unroll
                for (int j = 0; j < 8; ++j)
                    acc[i][j] = fmaf(xm[i], wn[j], acc[i][j]);
        }
        __syncthreads(); // compute done -> safe to overwrite LDS
        if (ch + 1 < NCH) commit(); // vmcnt wait lands HERE, after compute
    }

    // epilogue: n0<64 -> Y, else -> R; coalesced float4 row stores
    float* __restrict__ dbuf = (n0 < HID) ? Y : R;
    const int nc = n0 & (HID - 1);
#pragma unroll
    for (int i = 0; i < 8; ++i) {
        const int gn = nodeBase + m0 + i;
        if (gn < n) {
            float4 lo = make_float4(acc[i][0], acc[i][1], acc[i][2], acc[i][3]);
            float4 hi = make_float4(acc[i][4], acc[i][5], acc[i][6], acc[i][7]);
            *(float4*)&dbuf[(size_t)gn * HID + nc] = lo;
            *(float4*)&dbuf[(size_t)gn * HID + nc + 4] = hi;
        }
    }
}

// ---------------- aggregation (+ optional fused classifier) ----------------
// Wave per node, float2 per lane: lanes 0-31 process edge i, lanes 32-63
// edge i+1; halves merged with shfl_xor(32); redistribute shuffles kept in
// uniform control flow (EXEC-gated ds_bpermute — round-5 bug).

template <bool CLS>
__global__ __launch_bounds__(256) void k_agg(const float* __restrict__ Y,
                                             const float* __restrict__ Rm,
                                             const float* __restrict__ bias,
                                             const int* __restrict__ rowptr,
                                             const int* __restrict__ col,
                                             float* __restrict__ H,
                                             const float* __restrict__ Wc,
                                             const float* __restrict__ bc,
                                             float* __restrict__ out, int n) {
    const int lane = threadIdx.x & 63;
    const int node = blockIdx.x * 4 + (threadIdx.x >> 6);
    if (node >= n) return;
    const int half = lane >> 5;        // which edge of the pair
    const int fl = (lane & 31) * 2;    // feature pair
    const int s = rowptr[node], e = rowptr[node + 1];
    float ax = 0.f, ay = 0.f;
    int i = s + half;
    for (; i + 6 < e; i += 8) {
        int s0 = col[i], s1 = col[i + 2], s2 = col[i + 4], s3 = col[i + 6];
        float2 y0 = *(const float2*)&Y[(size_t)s0 * HID + fl];
        float2 y1 = *(const float2*)&Y[(size_t)s1 * HID + fl];
        float2 y2 = *(const float2*)&Y[(size_t)s2 * HID + fl];
        float2 y3 = *(const float2*)&Y[(size_t)s3 * HID + fl];
        ax += (y0.x + y1.x) + (y2.x + y3.x);
        ay += (y0.y + y1.y) + (y2.y + y3.y);
    }
    for (; i < e; i += 2) {
        float2 yv = *(const float2*)&Y[(size_t)col[i] * HID + fl];
        ax += yv.x;
        ay += yv.y;
    }
    ax += __shfl_xor(ax, 32, 64);
    ay += __shfl_xor(ay, 32, 64);
    const float vx = __shfl(ax, lane >> 1, 64);
    const float vy = __shfl(ay, lane >> 1, 64);
    const float acc = (lane & 1) ? vy : vx;
    const int deg = e - s;
    float h = acc / (float)(deg > 1 ? deg : 1) + bias[lane] + Rm[(size_t)node * HID + lane];
    h = fmaxf(h, 0.f);
    if (!CLS) {
        H[(size_t)node * HID + lane] = h;
    } else {
        float p0 = h * Wc[lane * 2 + 0];
        float p1 = h * Wc[lane * 2 + 1];
#pragma unroll
        for (int off = 32; off > 0; off >>= 1) {
            p0 += __shfl_xor(p0, off, 64);
            p1 += __shfl_xor(p1, off, 64);
        }
        if (lane == 0) {
            out[(size_t)node * 2 + 0] = p0 + bc[0];
            out[(size_t)node * 2 + 1] = p1 + bc[1];
        }
    }
}

// ---------------- launch ----------------

extern "C" void kernel_launch(void* const* d_in, const int* in_sizes, int n_in,
                              void* d_out, int out_size, void* d_ws, size_t ws_size,
                              hipStream_t stream) {
    const float* x   = (const float*)d_in[0];
    const int*   ei  = (const int*)d_in[1];
    const float* W1l = (const float*)d_in[2];
    const float* b1  = (const float*)d_in[3];
    const float* W1r = (const float*)d_in[4];
    const float* W2l = (const float*)d_in[5];
    const float* b2  = (const float*)d_in[6];
    const float* W2r = (const float*)d_in[7];
    const float* Wc  = (const float*)d_in[8];
    const float* bc  = (const float*)d_in[9];
    float* out = (float*)d_out;
    const int* src = ei;
    const int* dst = ei + NE;

    char* base = (char*)d_ws;
    size_t off = 0;
    auto alloc = [&](size_t bytes) {
        void* p = base + off;
        off = (off + bytes + 255) & ~(size_t)255;
        return p;
    };
    int*   bhist   = (int*)alloc((size_t)NBUK * 4);
    int*   bbase   = (int*)alloc((size_t)(NBUK + 1) * 4);
    int*   bcursor = (int*)alloc((size_t)NBUK * 4);
    int*   rowptr  = (int*)alloc((size_t)(NN + 1) * 4);
    int*   col     = (int*)alloc((size_t)NE * 4);
    // E2 (12.8 MB) is dead after k_csrb -> alias it under Y (25.6 MB)
    float* Y       = (float*)alloc((size_t)NN * HID * 4);
    float* R       = (float*)alloc((size_t)NN * HID * 4);
    float* H1      = (float*)alloc((size_t)NN * HID * 4);
    int2*  E2      = (int2*)Y;

    const int sb = (NE + SC_CHUNK - 1) / SC_CHUNK; // 196

    hipMemsetAsync(bhist, 0, (size_t)NBUK * 4, stream);
    k_bhist<<<sb, 256, 0, stream>>>(dst, bhist, NE);
    k_bscan<<<1, 256, 0, stream>>>(bhist, bbase, bcursor);
    k_scatter<<<sb, 256, 0, stream>>>(src, dst, bcursor, E2, NE);
    k_csrb<<<NBUK, 256, 0, stream>>>(E2, bbase, rowptr, col, NN);

    k_linear<INDIM><<<(NN + 127) / 128, 256, 0, stream>>>(x, W1l, W1r, Y, R, NN);
    k_agg<false><<<(NN + 3) / 4, 256, 0, stream>>>(Y, R, b1, rowptr, col, H1,
                                                   nullptr, nullptr, nullptr, NN);
    k_linear<HID><<<(NN + 127) / 128, 256, 0, stream>>>(H1, W2l, W2r, Y, R, NN);
    k_agg<true><<<(NN + 3) / 4, 256, 0, stream>>>(Y, R, b2, rowptr, col, nullptr,
                                                  Wc, bc, out, NN);
}

// Round 11
// 405.148 us; speedup vs baseline: 1.3824x; 1.0285x over previous
//
#include <hip/hip_runtime.h>
#include <cstdint>

#define NN 100000
#define NE 1600000
#define INDIM 165
#define HID 64

// dst-bucket partition: bucket = dst >> BSH, BNODES nodes per bucket
constexpr int BSH = 7;
constexpr int BNODES = 128;               // 1 << BSH
constexpr int NBUK = (NN + BNODES - 1) / BNODES; // 782
constexpr int SC_CHUNK = 8192;            // edges per scatter block

// ---------------- bucket histogram ----------------

__global__ __launch_bounds__(256) void k_bhist(const int* __restrict__ dst,
                                               int* __restrict__ bhist, int ne) {
    __shared__ int h[NBUK];
    for (int b = threadIdx.x; b < NBUK; b += 256) h[b] = 0;
    __syncthreads();
    for (int e = blockIdx.x * blockDim.x + threadIdx.x; e < ne;
         e += gridDim.x * blockDim.x)
        atomicAdd(&h[dst[e] >> BSH], 1);
    __syncthreads();
    for (int b = threadIdx.x; b < NBUK; b += 256)
        if (h[b]) atomicAdd(&bhist[b], h[b]);
}

// ---------------- scan of 782 bucket counts (single block) ----------------

__global__ __launch_bounds__(256) void k_bscan(const int* __restrict__ bhist,
                                               int* __restrict__ bbase,
                                               int* __restrict__ bcursor) {
    __shared__ int wsum[4];
    const int tid = threadIdx.x, lane = tid & 63, wid = tid >> 6;
    int v[4];
    int tsum = 0;
#pragma unroll
    for (int i = 0; i < 4; ++i) {
        int idx = tid * 4 + i;
        v[i] = (idx < NBUK) ? bhist[idx] : 0;
        tsum += v[i];
    }
    int x = tsum;
#pragma unroll
    for (int off = 1; off < 64; off <<= 1) {
        int y = __shfl_up(x, off, 64);
        if (lane >= off) x += y;
    }
    if (lane == 63) wsum[wid] = x;
    __syncthreads();
    int woff = 0;
#pragma unroll
    for (int w = 0; w < 4; ++w)
        if (w < wid) woff += wsum[w];
    int run = woff + x - tsum;
#pragma unroll
    for (int i = 0; i < 4; ++i) {
        int idx = tid * 4 + i;
        if (idx < NBUK) { bbase[idx] = run; bcursor[idx] = run; }
        run += v[i];
    }
    if (tid == 255) bbase[NBUK] = woff + x; // grand total (= ne)
}

// ---------------- partition edges into bucket-major (src,dst) pairs --------

__global__ __launch_bounds__(256) void k_scatter(const int* __restrict__ src,
                                                 const int* __restrict__ dst,
                                                 int* __restrict__ bcursor,
                                                 int2* __restrict__ E2, int ne) {
    __shared__ int hist[NBUK];
    __shared__ int base[NBUK];
    const int tid = threadIdx.x;
    const int cs = blockIdx.x * SC_CHUNK;
    for (int b = tid; b < NBUK; b += 256) hist[b] = 0;
    __syncthreads();
    unsigned pack[SC_CHUNK / 256];
#pragma unroll 8
    for (int i = 0; i < SC_CHUNK / 256; ++i) {
        int e = cs + i * 256 + tid;
        if (e < ne) {
            int b = dst[e] >> BSH;
            int r = atomicAdd(&hist[b], 1);      // rank within (block,bucket)
            pack[i] = (unsigned)((b << 13) | r); // b<=781 (10b), r<8192 (13b)
        } else {
            pack[i] = 0xFFFFFFFFu;
        }
    }
    __syncthreads();
    for (int b = tid; b < NBUK; b += 256) {
        int c = hist[b];
        base[b] = c ? atomicAdd(&bcursor[b], c) : 0;
    }
    __syncthreads();
#pragma unroll 8
    for (int i = 0; i < SC_CHUNK / 256; ++i) {
        if (pack[i] != 0xFFFFFFFFu) {
            int e = cs + i * 256 + tid;
            int b = pack[i] >> 13, r = pack[i] & 8191;
            E2[base[b] + r] = make_int2(src[e], dst[e]);
        }
    }
}

// ---------------- per-bucket CSR build ----------------

__global__ __launch_bounds__(256) void k_csrb(const int2* __restrict__ E2,
                                              const int* __restrict__ bbase,
                                              int* __restrict__ rowptr,
                                              int* __restrict__ col, int n) {
    __shared__ int cnt[BNODES];
    __shared__ int pref[BNODES];
    const int tid = threadIdx.x;
    const int bs = bbase[blockIdx.x], be = bbase[blockIdx.x + 1];
    for (int i = tid; i < BNODES; i += 256) cnt[i] = 0;
    __syncthreads();
    for (int e = bs + tid; e < be; e += 256)
        atomicAdd(&cnt[E2[e].y & (BNODES - 1)], 1);
    __syncthreads();
    if (tid < 64) { // wave 0 scans 128 counts, 2/lane (wave-uniform branch)
        int c0 = cnt[tid * 2], c1 = cnt[tid * 2 + 1];
        int s = c0 + c1;
        int x = s;
#pragma unroll
        for (int off = 1; off < 64; off <<= 1) {
            int y = __shfl_up(x, off, 64);
            if (tid >= off) x += y;
        }
        int ex = x - s; // exclusive
        pref[tid * 2] = ex;
        pref[tid * 2 + 1] = ex + c0;
    }
    __syncthreads();
    const int nodeBase = blockIdx.x * BNODES;
    for (int i = tid; i < BNODES; i += 256) {
        int gn = nodeBase + i;
        if (gn < n) rowptr[gn] = bs + pref[i];
        cnt[i] = 0; // reuse as cursor
    }
    __syncthreads();
    for (int e = bs + tid; e < be; e += 256) {
        int2 pr = E2[e];
        int d = pr.y & (BNODES - 1);
        int r = atomicAdd(&cnt[d], 1);
        col[bs + pref[d] + r] = pr.x;
    }
    if (blockIdx.x == 0 && tid == 0) rowptr[n] = bbase[NBUK];
}

// ---------------- fused dual linear: Y = X@Wl, R = X@Wr ----------------
// Register-tiled GEMM, MT=64 for OCCUPANCY. r6/r9/r10 all plateaued at
// ~100 us with VALUBusy ~36% and occupancy 15-19%: MT=128 -> only 782
// blocks (~3/CU, ~6 waves/CU resident) -> nothing hides LDS/global
// latency, independent of K-loop structure (plain / conflict-fixed /
// register-prefetch all identical). Fix: MT=64 -> 1563 blocks, LDS 25 KB
// -> 6 blocks/CU (24 waves/CU, ~75% occupancy ceiling), VGPR ~64.
// Microtile 4x8 (32 acc): per kk = 3 ds_read_b128 / 32 FMA; X reads are
// 16-way broadcast, W reads use the r9 split lo/hi layout (2-way, free).

template <int K>
__global__ __launch_bounds__(256) void k_linear(const float* __restrict__ X,
                                                const float* __restrict__ Wl,
                                                const float* __restrict__ Wr,
                                                float* __restrict__ Y,
                                                float* __restrict__ R, int n) {
    constexpr int KC = 32;
    constexpr int MT = 64;
    constexpr int LDX = 68; // +4 pad
    __shared__ float Xs[KC][LDX]; // Xs[k][m]
    __shared__ float Ws[KC][128]; // split lo/hi layout

    const int tid = threadIdx.x;
    const int m0 = (tid >> 4) * 4;  // 4 nodes per thread
    const int n0 = (tid & 15) * 8;  // 8 cols per thread
    const int nodeBase = blockIdx.x * MT;

    float acc[4][8];
#pragma unroll
    for (int i = 0; i < 4; ++i)
#pragma unroll
        for (int j = 0; j < 8; ++j) acc[i][j] = 0.f;

    for (int c = 0; c < K; c += KC) {
        const int kw = (K - c < KC) ? (K - c) : KC;
        __syncthreads();
        // stage X: e -> k = e&31 (consec lanes = consec k: coalesced), m = e>>5
#pragma unroll
        for (int i = 0; i < 8; ++i) {
            int e = tid + i * 256;
            int k = e & 31;
            int m = e >> 5;
            int gn = nodeBase + m;
            if (gn >= n) gn = n - 1;
            Xs[k][m] = (k < kw) ? X[(size_t)gn * K + c + k] : 0.f;
        }
        // stage W: logical float4 col nf -> split lo/hi position
#pragma unroll
        for (int i = 0; i < 4; ++i) {
            int v = tid + i * 256;
            int k = v >> 5;
            int nf = (v & 31) * 4;
            float4 w;
            if (k < kw) {
                const float* sp = (nf < 64) ? (Wl + (size_t)(c + k) * HID + nf)
                                            : (Wr + (size_t)(c + k) * HID + (nf - 64));
                w = *(const float4*)sp;
            } else {
                w = make_float4(0.f, 0.f, 0.f, 0.f);
            }
            const int pos = ((nf >> 2) & 1) * 64 + (nf >> 3) * 4;
            *(float4*)&Ws[k][pos] = w;
        }
        __syncthreads();
#pragma unroll 4
        for (int kk = 0; kk < KC; ++kk) {
            const float4 xa = *(const float4*)&Xs[kk][m0];
            const float4 wa = *(const float4*)&Ws[kk][n0 >> 1];        // lo
            const float4 wb = *(const float4*)&Ws[kk][64 + (n0 >> 1)]; // hi
            const float xm[4] = {xa.x, xa.y, xa.z, xa.w};
            const float wn[8] = {wa.x, wa.y, wa.z, wa.w, wb.x, wb.y, wb.z, wb.w};
#pragma unroll
            for (int i = 0; i < 4; ++i)
#pragma unroll
                for (int j = 0; j < 8; ++j)
                    acc[i][j] = fmaf(xm[i], wn[j], acc[i][j]);
        }
    }

    // epilogue: n0<64 -> Y, else -> R; coalesced float4 row stores
    float* __restrict__ dbuf = (n0 < HID) ? Y : R;
    const int nc = n0 & (HID - 1);
#pragma unroll
    for (int i = 0; i < 4; ++i) {
        const int gn = nodeBase + m0 + i;
        if (gn < n) {
            float4 lo = make_float4(acc[i][0], acc[i][1], acc[i][2], acc[i][3]);
            float4 hi = make_float4(acc[i][4], acc[i][5], acc[i][6], acc[i][7]);
            *(float4*)&dbuf[(size_t)gn * HID + nc] = lo;
            *(float4*)&dbuf[(size_t)gn * HID + nc + 4] = hi;
        }
    }
}

// ---------------- aggregation (+ optional fused classifier) ----------------
// Wave per node, float2 per lane: lanes 0-31 process edge i, lanes 32-63
// edge i+1; halves merged with shfl_xor(32); redistribute shuffles kept in
// uniform control flow (EXEC-gated ds_bpermute — round-5 bug).

template <bool CLS>
__global__ __launch_bounds__(256) void k_agg(const float* __restrict__ Y,
                                             const float* __restrict__ Rm,
                                             const float* __restrict__ bias,
                                             const int* __restrict__ rowptr,
                                             const int* __restrict__ col,
                                             float* __restrict__ H,
                                             const float* __restrict__ Wc,
                                             const float* __restrict__ bc,
                                             float* __restrict__ out, int n) {
    const int lane = threadIdx.x & 63;
    const int node = blockIdx.x * 4 + (threadIdx.x >> 6);
    if (node >= n) return;
    const int half = lane >> 5;        // which edge of the pair
    const int fl = (lane & 31) * 2;    // feature pair
    const int s = rowptr[node], e = rowptr[node + 1];
    float ax = 0.f, ay = 0.f;
    int i = s + half;
    for (; i + 6 < e; i += 8) {
        int s0 = col[i], s1 = col[i + 2], s2 = col[i + 4], s3 = col[i + 6];
        float2 y0 = *(const float2*)&Y[(size_t)s0 * HID + fl];
        float2 y1 = *(const float2*)&Y[(size_t)s1 * HID + fl];
        float2 y2 = *(const float2*)&Y[(size_t)s2 * HID + fl];
        float2 y3 = *(const float2*)&Y[(size_t)s3 * HID + fl];
        ax += (y0.x + y1.x) + (y2.x + y3.x);
        ay += (y0.y + y1.y) + (y2.y + y3.y);
    }
    for (; i < e; i += 2) {
        float2 yv = *(const float2*)&Y[(size_t)col[i] * HID + fl];
        ax += yv.x;
        ay += yv.y;
    }
    ax += __shfl_xor(ax, 32, 64);
    ay += __shfl_xor(ay, 32, 64);
    const float vx = __shfl(ax, lane >> 1, 64);
    const float vy = __shfl(ay, lane >> 1, 64);
    const float acc = (lane & 1) ? vy : vx;
    const int deg = e - s;
    float h = acc / (float)(deg > 1 ? deg : 1) + bias[lane] + Rm[(size_t)node * HID + lane];
    h = fmaxf(h, 0.f);
    if (!CLS) {
        H[(size_t)node * HID + lane] = h;
    } else {
        float p0 = h * Wc[lane * 2 + 0];
        float p1 = h * Wc[lane * 2 + 1];
#pragma unroll
        for (int off = 32; off > 0; off >>= 1) {
            p0 += __shfl_xor(p0, off, 64);
            p1 += __shfl_xor(p1, off, 64);
        }
        if (lane == 0) {
            out[(size_t)node * 2 + 0] = p0 + bc[0];
            out[(size_t)node * 2 + 1] = p1 + bc[1];
        }
    }
}

// ---------------- launch ----------------

extern "C" void kernel_launch(void* const* d_in, const int* in_sizes, int n_in,
                              void* d_out, int out_size, void* d_ws, size_t ws_size,
                              hipStream_t stream) {
    const float* x   = (const float*)d_in[0];
    const int*   ei  = (const int*)d_in[1];
    const float* W1l = (const float*)d_in[2];
    const float* b1  = (const float*)d_in[3];
    const float* W1r = (const float*)d_in[4];
    const float* W2l = (const float*)d_in[5];
    const float* b2  = (const float*)d_in[6];
    const float* W2r = (const float*)d_in[7];
    const float* Wc  = (const float*)d_in[8];
    const float* bc  = (const float*)d_in[9];
    float* out = (float*)d_out;
    const int* src = ei;
    const int* dst = ei + NE;

    char* base = (char*)d_ws;
    size_t off = 0;
    auto alloc = [&](size_t bytes) {
        void* p = base + off;
        off = (off + bytes + 255) & ~(size_t)255;
        return p;
    };
    int*   bhist   = (int*)alloc((size_t)NBUK * 4);
    int*   bbase   = (int*)alloc((size_t)(NBUK + 1) * 4);
    int*   bcursor = (int*)alloc((size_t)NBUK * 4);
    int*   rowptr  = (int*)alloc((size_t)(NN + 1) * 4);
    int*   col     = (int*)alloc((size_t)NE * 4);
    // E2 (12.8 MB) is dead after k_csrb -> alias it under Y (25.6 MB)
    float* Y       = (float*)alloc((size_t)NN * HID * 4);
    float* R       = (float*)alloc((size_t)NN * HID * 4);
    float* H1      = (float*)alloc((size_t)NN * HID * 4);
    int2*  E2      = (int2*)Y;

    const int sb = (NE + SC_CHUNK - 1) / SC_CHUNK; // 196

    hipMemsetAsync(bhist, 0, (size_t)NBUK * 4, stream);
    k_bhist<<<sb, 256, 0, stream>>>(dst, bhist, NE);
    k_bscan<<<1, 256, 0, stream>>>(bhist, bbase, bcursor);
    k_scatter<<<sb, 256, 0, stream>>>(src, dst, bcursor, E2, NE);
    k_csrb<<<NBUK, 256, 0, stream>>>(E2, bbase, rowptr, col, NN);

    k_linear<INDIM><<<(NN + 63) / 64, 256, 0, stream>>>(x, W1l, W1r, Y, R, NN);
    k_agg<false><<<(NN + 3) / 4, 256, 0, stream>>>(Y, R, b1, rowptr, col, H1,
                                                   nullptr, nullptr, nullptr, NN);
    k_linear<HID><<<(NN + 63) / 64, 256, 0, stream>>>(H1, W2l, W2r, Y, R, NN);
    k_agg<true><<<(NN + 3) / 4, 256, 0, stream>>>(Y, R, b2, rowptr, col, nullptr,
                                                  Wc, bc, out, NN);
}

// Round 12
// 385.798 us; speedup vs baseline: 1.4517x; 1.0502x over previous
//
#include <hip/hip_runtime.h>
#include <hip/hip_fp16.h>
#include <cstdint>

#define NN 100000
#define NE 1600000
#define INDIM 165
#define HID 64

// dst-bucket partition: bucket = dst >> BSH, BNODES nodes per bucket
constexpr int BSH = 7;
constexpr int BNODES = 128;               // 1 << BSH
constexpr int NBUK = (NN + BNODES - 1) / BNODES; // 782
constexpr int SC_CHUNK = 8192;            // edges per scatter block

// ---------------- bucket histogram ----------------

__global__ __launch_bounds__(256) void k_bhist(const int* __restrict__ dst,
                                               int* __restrict__ bhist, int ne) {
    __shared__ int h[NBUK];
    for (int b = threadIdx.x; b < NBUK; b += 256) h[b] = 0;
    __syncthreads();
    for (int e = blockIdx.x * blockDim.x + threadIdx.x; e < ne;
         e += gridDim.x * blockDim.x)
        atomicAdd(&h[dst[e] >> BSH], 1);
    __syncthreads();
    for (int b = threadIdx.x; b < NBUK; b += 256)
        if (h[b]) atomicAdd(&bhist[b], h[b]);
}

// ---------------- scan of 782 bucket counts (single block) ----------------

__global__ __launch_bounds__(256) void k_bscan(const int* __restrict__ bhist,
                                               int* __restrict__ bbase,
                                               int* __restrict__ bcursor) {
    __shared__ int wsum[4];
    const int tid = threadIdx.x, lane = tid & 63, wid = tid >> 6;
    int v[4];
    int tsum = 0;
#pragma unroll
    for (int i = 0; i < 4; ++i) {
        int idx = tid * 4 + i;
        v[i] = (idx < NBUK) ? bhist[idx] : 0;
        tsum += v[i];
    }
    int x = tsum;
#pragma unroll
    for (int off = 1; off < 64; off <<= 1) {
        int y = __shfl_up(x, off, 64);
        if (lane >= off) x += y;
    }
    if (lane == 63) wsum[wid] = x;
    __syncthreads();
    int woff = 0;
#pragma unroll
    for (int w = 0; w < 4; ++w)
        if (w < wid) woff += wsum[w];
    int run = woff + x - tsum;
#pragma unroll
    for (int i = 0; i < 4; ++i) {
        int idx = tid * 4 + i;
        if (idx < NBUK) { bbase[idx] = run; bcursor[idx] = run; }
        run += v[i];
    }
    if (tid == 255) bbase[NBUK] = woff + x; // grand total (= ne)
}

// ---------------- partition edges into bucket-major (src,dst) pairs --------

__global__ __launch_bounds__(256) void k_scatter(const int* __restrict__ src,
                                                 const int* __restrict__ dst,
                                                 int* __restrict__ bcursor,
                                                 int2* __restrict__ E2, int ne) {
    __shared__ int hist[NBUK];
    __shared__ int base[NBUK];
    const int tid = threadIdx.x;
    const int cs = blockIdx.x * SC_CHUNK;
    for (int b = tid; b < NBUK; b += 256) hist[b] = 0;
    __syncthreads();
    unsigned pack[SC_CHUNK / 256];
#pragma unroll 8
    for (int i = 0; i < SC_CHUNK / 256; ++i) {
        int e = cs + i * 256 + tid;
        if (e < ne) {
            int b = dst[e] >> BSH;
            int r = atomicAdd(&hist[b], 1);      // rank within (block,bucket)
            pack[i] = (unsigned)((b << 13) | r); // b<=781 (10b), r<8192 (13b)
        } else {
            pack[i] = 0xFFFFFFFFu;
        }
    }
    __syncthreads();
    for (int b = tid; b < NBUK; b += 256) {
        int c = hist[b];
        base[b] = c ? atomicAdd(&bcursor[b], c) : 0;
    }
    __syncthreads();
#pragma unroll 8
    for (int i = 0; i < SC_CHUNK / 256; ++i) {
        if (pack[i] != 0xFFFFFFFFu) {
            int e = cs + i * 256 + tid;
            int b = pack[i] >> 13, r = pack[i] & 8191;
            E2[base[b] + r] = make_int2(src[e], dst[e]);
        }
    }
}

// ---------------- per-bucket CSR build ----------------

__global__ __launch_bounds__(256) void k_csrb(const int2* __restrict__ E2,
                                              const int* __restrict__ bbase,
                                              int* __restrict__ rowptr,
                                              int* __restrict__ col, int n) {
    __shared__ int cnt[BNODES];
    __shared__ int pref[BNODES];
    const int tid = threadIdx.x;
    const int bs = bbase[blockIdx.x], be = bbase[blockIdx.x + 1];
    for (int i = tid; i < BNODES; i += 256) cnt[i] = 0;
    __syncthreads();
    for (int e = bs + tid; e < be; e += 256)
        atomicAdd(&cnt[E2[e].y & (BNODES - 1)], 1);
    __syncthreads();
    if (tid < 64) { // wave 0 scans 128 counts, 2/lane (wave-uniform branch)
        int c0 = cnt[tid * 2], c1 = cnt[tid * 2 + 1];
        int s = c0 + c1;
        int x = s;
#pragma unroll
        for (int off = 1; off < 64; off <<= 1) {
            int y = __shfl_up(x, off, 64);
            if (tid >= off) x += y;
        }
        int ex = x - s; // exclusive
        pref[tid * 2] = ex;
        pref[tid * 2 + 1] = ex + c0;
    }
    __syncthreads();
    const int nodeBase = blockIdx.x * BNODES;
    for (int i = tid; i < BNODES; i += 256) {
        int gn = nodeBase + i;
        if (gn < n) rowptr[gn] = bs + pref[i];
        cnt[i] = 0; // reuse as cursor
    }
    __syncthreads();
    for (int e = bs + tid; e < be; e += 256) {
        int2 pr = E2[e];
        int d = pr.y & (BNODES - 1);
        int r = atomicAdd(&cnt[d], 1);
        col[bs + pref[d] + r] = pr.x;
    }
    if (blockIdx.x == 0 && tid == 0) rowptr[n] = bbase[NBUK];
}

// ---------------- fused dual linear: Y(fp16) = X@Wl, R(fp32) = X@Wr -------
// MT=64 register-tiled GEMM. r11 post-mortem: LDS-BW bound — per kk per
// wave, unique LDS traffic was W 16x32B + X 4x16B = 576B per 32-FMA group
// -> VALU duty model 2048/4608 = 44% (measured 47%). Fix: SWAP the
// thread->tile mapping: m0 = (tid&15)*4 (16 distinct X addrs, stride 16B
// -> 2-way banks, free), n0 = (tid>>4)*8 (only 4 distinct W addr-pairs
// per wave -> broadcast). Unique bytes 576 -> 384/kk/wave.
// Y stored fp16 (halves k_agg's gather traffic); R stays fp32.

template <int K>
__global__ __launch_bounds__(256) void k_linear(const float* __restrict__ X,
                                                const float* __restrict__ Wl,
                                                const float* __restrict__ Wr,
                                                __half* __restrict__ Y,
                                                float* __restrict__ R, int n) {
    constexpr int KC = 32;
    constexpr int MT = 64;
    constexpr int LDX = 68; // +4 pad
    __shared__ float Xs[KC][LDX]; // Xs[k][m]
    __shared__ float Ws[KC][128]; // split lo/hi layout (r9)

    const int tid = threadIdx.x;
    const int m0 = (tid & 15) * 4;  // node group: 16 distinct per wave
    const int n0 = (tid >> 4) * 8;  // col group: 4 distinct per wave
    const int nodeBase = blockIdx.x * MT;

    float acc[4][8];
#pragma unroll
    for (int i = 0; i < 4; ++i)
#pragma unroll
        for (int j = 0; j < 8; ++j) acc[i][j] = 0.f;

    for (int c = 0; c < K; c += KC) {
        const int kw = (K - c < KC) ? (K - c) : KC;
        __syncthreads();
        // stage X: e -> k = e&31 (consec lanes = consec k: coalesced), m = e>>5
#pragma unroll
        for (int i = 0; i < 8; ++i) {
            int e = tid + i * 256;
            int k = e & 31;
            int m = e >> 5;
            int gn = nodeBase + m;
            if (gn >= n) gn = n - 1;
            Xs[k][m] = (k < kw) ? X[(size_t)gn * K + c + k] : 0.f;
        }
        // stage W: logical float4 col nf -> split lo/hi position
#pragma unroll
        for (int i = 0; i < 4; ++i) {
            int v = tid + i * 256;
            int k = v >> 5;
            int nf = (v & 31) * 4;
            float4 w;
            if (k < kw) {
                const float* sp = (nf < 64) ? (Wl + (size_t)(c + k) * HID + nf)
                                            : (Wr + (size_t)(c + k) * HID + (nf - 64));
                w = *(const float4*)sp;
            } else {
                w = make_float4(0.f, 0.f, 0.f, 0.f);
            }
            const int pos = ((nf >> 2) & 1) * 64 + (nf >> 3) * 4;
            *(float4*)&Ws[k][pos] = w;
        }
        __syncthreads();
#pragma unroll 4
        for (int kk = 0; kk < KC; ++kk) {
            const float4 xa = *(const float4*)&Xs[kk][m0];
            const float4 wa = *(const float4*)&Ws[kk][n0 >> 1];        // lo
            const float4 wb = *(const float4*)&Ws[kk][64 + (n0 >> 1)]; // hi
            const float xm[4] = {xa.x, xa.y, xa.z, xa.w};
            const float wn[8] = {wa.x, wa.y, wa.z, wa.w, wb.x, wb.y, wb.z, wb.w};
#pragma unroll
            for (int i = 0; i < 4; ++i)
#pragma unroll
                for (int j = 0; j < 8; ++j)
                    acc[i][j] = fmaf(xm[i], wn[j], acc[i][j]);
        }
    }

    // epilogue: n0<64 -> Y (fp16, one 16B packed store), else -> R (fp32)
    if (n0 < HID) {
#pragma unroll
        for (int i = 0; i < 4; ++i) {
            const int gn = nodeBase + m0 + i;
            if (gn < n) {
                union { __half2 h2[4]; uint4 u4; } u;
#pragma unroll
                for (int q = 0; q < 4; ++q)
                    u.h2[q] = __float22half2_rn(
                        make_float2(acc[i][2 * q], acc[i][2 * q + 1]));
                *(uint4*)&Y[(size_t)gn * HID + n0] = u.u4; // 16B aligned
            }
        }
    } else {
        const int nc = n0 - HID;
#pragma unroll
        for (int i = 0; i < 4; ++i) {
            const int gn = nodeBase + m0 + i;
            if (gn < n) {
                *(float4*)&R[(size_t)gn * HID + nc] =
                    make_float4(acc[i][0], acc[i][1], acc[i][2], acc[i][3]);
                *(float4*)&R[(size_t)gn * HID + nc + 4] =
                    make_float4(acc[i][4], acc[i][5], acc[i][6], acc[i][7]);
            }
        }
    }
}

// ---------------- aggregation (+ optional fused classifier) ----------------
// Wave per node; Y is fp16 -> each lane reads a __half2 (half-wave covers a
// whole 128B row, half the bytes of the fp32 version). Lanes 0-31 process
// edge i, lanes 32-63 edge i+1; halves merged with shfl_xor(32);
// redistribute shuffles in uniform CF (EXEC-gated ds_bpermute, r5 bug).

template <bool CLS>
__global__ __launch_bounds__(256) void k_agg(const __half* __restrict__ Y,
                                             const float* __restrict__ Rm,
                                             const float* __restrict__ bias,
                                             const int* __restrict__ rowptr,
                                             const int* __restrict__ col,
                                             float* __restrict__ H,
                                             const float* __restrict__ Wc,
                                             const float* __restrict__ bc,
                                             float* __restrict__ out, int n) {
    const int lane = threadIdx.x & 63;
    const int node = blockIdx.x * 4 + (threadIdx.x >> 6);
    if (node >= n) return;
    const int half_ = lane >> 5;       // which edge of the pair
    const int fl = (lane & 31) * 2;    // feature pair
    const int s = rowptr[node], e = rowptr[node + 1];
    float ax = 0.f, ay = 0.f;
    int i = s + half_;
    for (; i + 6 < e; i += 8) {
        int s0 = col[i], s1 = col[i + 2], s2 = col[i + 4], s3 = col[i + 6];
        float2 y0 = __half22float2(*(const __half2*)&Y[(size_t)s0 * HID + fl]);
        float2 y1 = __half22float2(*(const __half2*)&Y[(size_t)s1 * HID + fl]);
        float2 y2 = __half22float2(*(const __half2*)&Y[(size_t)s2 * HID + fl]);
        float2 y3 = __half22float2(*(const __half2*)&Y[(size_t)s3 * HID + fl]);
        ax += (y0.x + y1.x) + (y2.x + y3.x);
        ay += (y0.y + y1.y) + (y2.y + y3.y);
    }
    for (; i < e; i += 2) {
        float2 yv = __half22float2(*(const __half2*)&Y[(size_t)col[i] * HID + fl]);
        ax += yv.x;
        ay += yv.y;
    }
    ax += __shfl_xor(ax, 32, 64);
    ay += __shfl_xor(ay, 32, 64);
    const float vx = __shfl(ax, lane >> 1, 64);
    const float vy = __shfl(ay, lane >> 1, 64);
    const float acc = (lane & 1) ? vy : vx;
    const int deg = e - s;
    float h = acc / (float)(deg > 1 ? deg : 1) + bias[lane] + Rm[(size_t)node * HID + lane];
    h = fmaxf(h, 0.f);
    if (!CLS) {
        H[(size_t)node * HID + lane] = h;
    } else {
        float p0 = h * Wc[lane * 2 + 0];
        float p1 = h * Wc[lane * 2 + 1];
#pragma unroll
        for (int off = 32; off > 0; off >>= 1) {
            p0 += __shfl_xor(p0, off, 64);
            p1 += __shfl_xor(p1, off, 64);
        }
        if (lane == 0) {
            out[(size_t)node * 2 + 0] = p0 + bc[0];
            out[(size_t)node * 2 + 1] = p1 + bc[1];
        }
    }
}

// ---------------- launch ----------------

extern "C" void kernel_launch(void* const* d_in, const int* in_sizes, int n_in,
                              void* d_out, int out_size, void* d_ws, size_t ws_size,
                              hipStream_t stream) {
    const float* x   = (const float*)d_in[0];
    const int*   ei  = (const int*)d_in[1];
    const float* W1l = (const float*)d_in[2];
    const float* b1  = (const float*)d_in[3];
    const float* W1r = (const float*)d_in[4];
    const float* W2l = (const float*)d_in[5];
    const float* b2  = (const float*)d_in[6];
    const float* W2r = (const float*)d_in[7];
    const float* Wc  = (const float*)d_in[8];
    const float* bc  = (const float*)d_in[9];
    float* out = (float*)d_out;
    const int* src = ei;
    const int* dst = ei + NE;

    char* base = (char*)d_ws;
    size_t off = 0;
    auto alloc = [&](size_t bytes) {
        void* p = base + off;
        off = (off + bytes + 255) & ~(size_t)255;
        return p;
    };
    int*    bhist   = (int*)alloc((size_t)NBUK * 4);
    int*    bbase   = (int*)alloc((size_t)(NBUK + 1) * 4);
    int*    bcursor = (int*)alloc((size_t)NBUK * 4);
    int*    rowptr  = (int*)alloc((size_t)(NN + 1) * 4);
    int*    col     = (int*)alloc((size_t)NE * 4);
    // E2 (12.8 MB) is dead after k_csrb -> alias it under Y (fp16, 12.8 MB)
    __half* Y       = (__half*)alloc((size_t)NN * HID * 2 + 256);
    float*  R       = (float*)alloc((size_t)NN * HID * 4);
    float*  H1      = (float*)alloc((size_t)NN * HID * 4);
    int2*   E2      = (int2*)Y;

    const int sb = (NE + SC_CHUNK - 1) / SC_CHUNK; // 196

    hipMemsetAsync(bhist, 0, (size_t)NBUK * 4, stream);
    k_bhist<<<sb, 256, 0, stream>>>(dst, bhist, NE);
    k_bscan<<<1, 256, 0, stream>>>(bhist, bbase, bcursor);
    k_scatter<<<sb, 256, 0, stream>>>(src, dst, bcursor, E2, NE);
    k_csrb<<<NBUK, 256, 0, stream>>>(E2, bbase, rowptr, col, NN);

    k_linear<INDIM><<<(NN + 63) / 64, 256, 0, stream>>>(x, W1l, W1r, Y, R, NN);
    k_agg<false><<<(NN + 3) / 4, 256, 0, stream>>>(Y, R, b1, rowptr, col, H1,
                                                   nullptr, nullptr, nullptr, NN);
    k_linear<HID><<<(NN + 63) / 64, 256, 0, stream>>>(H1, W2l, W2r, Y, R, NN);
    k_agg<true><<<(NN + 3) / 4, 256, 0, stream>>>(Y, R, b2, rowptr, col, nullptr,
                                                  Wc, bc, out, NN);
}